// Round 1
// baseline (515.353 us; speedup 1.0000x reference)
//
#include <hip/hip_runtime.h>
#include <cstdint>
#include <cstddef>

typedef __attribute__((ext_vector_type(4))) float f32x4;
typedef __attribute__((ext_vector_type(8))) short bf16x8;

typedef const __attribute__((address_space(1))) void* gas_ptr;
typedef __attribute__((address_space(3))) void* las_ptr;

static __device__ __forceinline__ short f2bf(float f) {
    union { float f; uint32_t u; } v; v.f = f;
    uint32_t r = v.u + 0x7fffu + ((v.u >> 16) & 1u);
    return (short)(r >> 16);
}

// ---------------- fp32 -> bf16 conversion ----------------
__global__ void cvt_f32_bf16(const float* __restrict__ src, short* __restrict__ dst, int n4) {
    int i = blockIdx.x * blockDim.x + threadIdx.x;
    const int stride = gridDim.x * blockDim.x;
    for (; i < n4; i += stride) {
        const float4 v = reinterpret_cast<const float4*>(src)[i];
        short4 o;
        o.x = f2bf(v.x); o.y = f2bf(v.y); o.z = f2bf(v.z); o.w = f2bf(v.w);
        reinterpret_cast<short4*>(dst)[i] = o;
    }
}

// ---------------- bf16 GEMM  C = A (MxK) * B^T (NxK), K=768 ----------------
// 128x128 tile, BK=64, 4 waves (2x2), global_load_lds staging with
// XOR-swizzled source (swizzle: byte ^= (row&7)<<4 within each 128B row).
// MODE 0: QKV epilogue -> scatter q(scaled)/k (B,H,388,64) and vT (B,H,64,392) bf16
// MODE 1: proj epilogue -> fp32 out + bias
template<int MODE>
__global__ __launch_bounds__(256) void gemm_bt(
    const short* __restrict__ A, const short* __restrict__ Bw,
    const float* __restrict__ bias,
    short* __restrict__ qo, short* __restrict__ ko, short* __restrict__ vo,
    float* __restrict__ fo)
{
    constexpr int K = 768;
    constexpr int KT = K / 64;
    __shared__ __align__(16) short ldsA[128 * 64];
    __shared__ __align__(16) short ldsB[128 * 64];

    const int tid  = threadIdx.x;
    const int lane = tid & 63;
    const int wid  = tid >> 6;
    const int lrow = lane & 15;
    const int lgrp = lane >> 4;
    const int wr   = wid >> 1;     // wave row (0..1)
    const int wc   = wid & 1;      // wave col (0..1)
    const int m0   = blockIdx.x * 128;
    const int n0   = blockIdx.y * 128;

    f32x4 acc[4][4];
    #pragma unroll
    for (int i = 0; i < 4; ++i)
        #pragma unroll
        for (int j = 0; j < 4; ++j)
            acc[i][j] = f32x4{0.f, 0.f, 0.f, 0.f};

    for (int kt = 0; kt < KT; ++kt) {
        // stage A-tile and B-tile (each 128x64 bf16 = 16KB = 1024 x 16B chunks)
        #pragma unroll
        for (int it = 0; it < 4; ++it) {
            const int c   = it * 256 + wid * 64 + lane;   // wave-contiguous chunks
            const int row = c >> 3;                        // 128B per LDS row
            const int cb  = (c & 7) * 16;                  // byte col in row
            const int scb = cb ^ ((row & 7) << 4);         // inverse swizzle on SOURCE
            const short* ga = A  + (size_t)(m0 + row) * K + kt * 64 + (scb >> 1);
            const short* gb = Bw + (size_t)(n0 + row) * K + kt * 64 + (scb >> 1);
            __builtin_amdgcn_global_load_lds((gas_ptr)ga, (las_ptr)((char*)ldsA + c * 16), 16, 0, 0);
            __builtin_amdgcn_global_load_lds((gas_ptr)gb, (las_ptr)((char*)ldsB + c * 16), 16, 0, 0);
        }
        __syncthreads();   // drains vmcnt (compiler-inserted) -> tiles ready

        #pragma unroll
        for (int ks = 0; ks < 2; ++ks) {
            bf16x8 af[4], bfv[4];
            #pragma unroll
            for (int i = 0; i < 4; ++i) {
                const int r   = wr * 64 + i * 16 + lrow;
                const int byt = r * 128 + ((ks * 64 + lgrp * 16) ^ ((r & 7) << 4));
                af[i] = *reinterpret_cast<const bf16x8*>((const char*)ldsA + byt);
            }
            #pragma unroll
            for (int j = 0; j < 4; ++j) {
                const int r   = wc * 64 + j * 16 + lrow;
                const int byt = r * 128 + ((ks * 64 + lgrp * 16) ^ ((r & 7) << 4));
                bfv[j] = *reinterpret_cast<const bf16x8*>((const char*)ldsB + byt);
            }
            #pragma unroll
            for (int i = 0; i < 4; ++i)
                #pragma unroll
                for (int j = 0; j < 4; ++j)
                    acc[i][j] = __builtin_amdgcn_mfma_f32_16x16x32_bf16(af[i], bfv[j], acc[i][j], 0, 0, 0);
        }
        __syncthreads();   // protect LDS before next stage
    }

    const int mb = m0 + wr * 64;
    const int nb = n0 + wc * 64;
    if constexpr (MODE == 0) {
        // c in [0,2304): which = c/768, h = (c%768)/64, d = c%64
        #pragma unroll
        for (int j = 0; j < 4; ++j) {
            const int c     = nb + j * 16 + lrow;
            const int which = c / 768;
            const int rem   = c - which * 768;
            const int hh    = rem >> 6;
            const int d     = rem & 63;
            const float sc  = (which == 0) ? 0.125f : 1.0f;   // fold D^-0.5 into q
            const float bv  = bias[c];
            #pragma unroll
            for (int i = 0; i < 4; ++i) {
                #pragma unroll
                for (int r = 0; r < 4; ++r) {
                    const int m  = mb + i * 16 + lgrp * 4 + r;
                    const int bb = m / 388;
                    const int nn = m - bb * 388;
                    const short o = f2bf((acc[i][j][r] + bv) * sc);
                    const size_t bh = (size_t)bb * 12 + hh;
                    if (which == 0)      qo[(bh * 388 + nn) * 64 + d] = o;
                    else if (which == 1) ko[(bh * 388 + nn) * 64 + d] = o;
                    else                 vo[(bh * 64 + d) * 392 + nn] = o;  // transposed, padded
                }
            }
        }
    } else {
        #pragma unroll
        for (int i = 0; i < 4; ++i) {
            #pragma unroll
            for (int r = 0; r < 4; ++r) {
                const int m = mb + i * 16 + lgrp * 4 + r;
                #pragma unroll
                for (int j = 0; j < 4; ++j) {
                    const int c = nb + j * 16 + lrow;
                    fo[(size_t)m * 768 + c] = acc[i][j][r] + bias[c];
                }
            }
        }
    }
}

// ---------------- attention ----------------
// One wave owns 16 query rows x all keys for one (b,h).
// NKT = number of 16-key tiles (must be even). q pre-scaled by D^-0.5.
template<int NKT>
__global__ __launch_bounds__(256) void attn_kernel(
    const short* __restrict__ qb, const short* __restrict__ kb,
    const short* __restrict__ vT, short* __restrict__ ao,
    int q_start, int q_len, int k_len)
{
    constexpr int PSTR = NKT * 16 + 8;   // padded P row stride (bf16 elems)
    __shared__ __align__(16) short plds[4][16 * PSTR];

    const int tid  = threadIdx.x;
    const int lane = tid & 63;
    const int wid  = tid >> 6;
    const int lrow = lane & 15;
    const int lgrp = lane >> 4;
    const int bh   = blockIdx.y;
    const int qend = q_start + q_len;
    const int q0   = q_start + blockIdx.x * 64 + wid * 16;
    if (q0 >= qend) return;   // no barriers in this kernel: safe

    // Q fragments (A-operand): lane holds Q[q0+lrow][lgrp*8 .. +7] per k-step
    const short* qbase = qb + (size_t)bh * 388 * 64;
    int qrow = q0 + lrow; if (qrow >= qend) qrow = qend - 1;
    bf16x8 qf[2];
    #pragma unroll
    for (int ks = 0; ks < 2; ++ks)
        qf[ks] = *reinterpret_cast<const bf16x8*>(qbase + qrow * 64 + ks * 32 + lgrp * 8);

    // S = Q K^T (scaled already). Lane holds S[q=lgrp*4+r][key=t*16+lrow].
    f32x4 sacc[NKT];
    #pragma unroll
    for (int t = 0; t < NKT; ++t) sacc[t] = f32x4{0.f, 0.f, 0.f, 0.f};
    const short* kbase = kb + (size_t)bh * 388 * 64;
    #pragma unroll
    for (int t = 0; t < NKT; ++t) {
        const int krow = t * 16 + lrow;
        const int kc   = krow < k_len ? krow : k_len - 1;
        const short* kp = kbase + kc * 64 + lgrp * 8;
        const bf16x8 k0 = *reinterpret_cast<const bf16x8*>(kp);
        const bf16x8 k1 = *reinterpret_cast<const bf16x8*>(kp + 32);
        sacc[t] = __builtin_amdgcn_mfma_f32_16x16x32_bf16(qf[0], k0, sacc[t], 0, 0, 0);
        sacc[t] = __builtin_amdgcn_mfma_f32_16x16x32_bf16(qf[1], k1, sacc[t], 0, 0, 0);
    }
    // mask invalid keys
    #pragma unroll
    for (int t = 0; t < NKT; ++t) {
        if (t * 16 + lrow >= k_len) {
            #pragma unroll
            for (int r = 0; r < 4; ++r) sacc[t][r] = -1e30f;
        }
    }
    // row max (reduce over tiles in-lane, then over the 16 key-lanes)
    float mr[4] = {-1e30f, -1e30f, -1e30f, -1e30f};
    #pragma unroll
    for (int t = 0; t < NKT; ++t)
        #pragma unroll
        for (int r = 0; r < 4; ++r) mr[r] = fmaxf(mr[r], sacc[t][r]);
    #pragma unroll
    for (int msk = 1; msk < 16; msk <<= 1)
        #pragma unroll
        for (int r = 0; r < 4; ++r) mr[r] = fmaxf(mr[r], __shfl_xor(mr[r], msk, 64));
    // exp + row sum
    float rs[4] = {0.f, 0.f, 0.f, 0.f};
    #pragma unroll
    for (int t = 0; t < NKT; ++t)
        #pragma unroll
        for (int r = 0; r < 4; ++r) {
            const float p = __expf(sacc[t][r] - mr[r]);
            sacc[t][r] = p;
            rs[r] += p;
        }
    #pragma unroll
    for (int msk = 1; msk < 16; msk <<= 1)
        #pragma unroll
        for (int r = 0; r < 4; ++r) rs[r] += __shfl_xor(rs[r], msk, 64);

    // write P (bf16) to per-wave LDS region: [16 q rows][NKT*16 keys]
    short* my = &plds[wid][0];
    #pragma unroll
    for (int t = 0; t < NKT; ++t)
        #pragma unroll
        for (int r = 0; r < 4; ++r)
            my[(lgrp * 4 + r) * PSTR + t * 16 + lrow] = f2bf(sacc[t][r]);

    // O = P * V  (A = P from LDS, B = vT rows = d, K-contig)
    f32x4 oacc[4];
    #pragma unroll
    for (int dt = 0; dt < 4; ++dt) oacc[dt] = f32x4{0.f, 0.f, 0.f, 0.f};
    const short* vbase = vT + (size_t)bh * 64 * 392;
    #pragma unroll
    for (int ks = 0; ks < NKT / 2; ++ks) {
        const bf16x8 pf = *reinterpret_cast<const bf16x8*>(my + lrow * PSTR + ks * 32 + lgrp * 8);
        #pragma unroll
        for (int dt = 0; dt < 4; ++dt) {
            const bf16x8 vf = *reinterpret_cast<const bf16x8*>(
                vbase + (size_t)(dt * 16 + lrow) * 392 + ks * 32 + lgrp * 8);
            oacc[dt] = __builtin_amdgcn_mfma_f32_16x16x32_bf16(pf, vf, oacc[dt], 0, 0, 0);
        }
    }

    const int b = bh / 12, h = bh - b * 12;
    float inv[4];
    #pragma unroll
    for (int r = 0; r < 4; ++r) inv[r] = 1.0f / rs[r];
    #pragma unroll
    for (int r = 0; r < 4; ++r) {
        const int qn = q0 + lgrp * 4 + r;
        if (qn < qend) {
            #pragma unroll
            for (int dt = 0; dt < 4; ++dt)
                ao[((size_t)b * 388 + qn) * 768 + h * 64 + dt * 16 + lrow] =
                    f2bf(oacc[dt][r] * inv[r]);
        }
    }
}

extern "C" void kernel_launch(void* const* d_in, const int* in_sizes, int n_in,
                              void* d_out, int out_size, void* d_ws, size_t ws_size,
                              hipStream_t stream) {
    (void)in_sizes; (void)n_in; (void)out_size; (void)ws_size;
    const float* x      = (const float*)d_in[0];
    const float* qkv_w  = (const float*)d_in[1];
    const float* qkv_b  = (const float*)d_in[2];
    const float* proj_w = (const float*)d_in[3];
    const float* proj_b = (const float*)d_in[4];
    float* out = (float*)d_out;

    // ---- workspace layout (bytes) ----
    // M = 64*388 = 24832 rows, C = 768
    const size_t SZ   = (size_t)24832 * 768;          // 19,070,976 elems
    char* ws = (char*)d_ws;
    short* xb      = (short*)(ws);                    // bf16 x  (aliased with attn-out)
    short* attn    = (short*)(ws);                    //   xb dead after QKV GEMM
    short* qbuf    = (short*)(ws + 2 * SZ);           // (B,H,388,64) bf16, pre-scaled
    short* kbuf    = (short*)(ws + 4 * SZ);           // (B,H,388,64) bf16
    short* vTbuf   = (short*)(ws + 6 * SZ);           // (B,H,64,392) bf16 (padded)
    const size_t VT_BYTES = (size_t)768 * 64 * 392 * 2 + 256;  // + OOB-read slack
    short* qwb     = (short*)(ws + 6 * SZ + VT_BYTES);            // 2304x768 bf16
    short* pwb     = (short*)(ws + 6 * SZ + VT_BYTES + (size_t)2304 * 768 * 2);

    // 1) fp32 -> bf16 conversions
    cvt_f32_bf16<<<2048, 256, 0, stream>>>(x,      xb,  (int)(SZ / 4));
    cvt_f32_bf16<<<512,  256, 0, stream>>>(qkv_w,  qwb, 2304 * 768 / 4);
    cvt_f32_bf16<<<256,  256, 0, stream>>>(proj_w, pwb, 768 * 768 / 4);

    // 2) QKV GEMM: (24832x768) @ (2304x768)^T -> scatter q/k/vT
    gemm_bt<0><<<dim3(194, 18), 256, 0, stream>>>(xb, qwb, qkv_b, qbuf, kbuf, vTbuf, nullptr);

    // 3) attention: mt (q rows 0..127, keys 0..127), s (q rows 128..387, keys 0..387)
    attn_kernel<8> <<<dim3(2, 768), 256, 0, stream>>>(qbuf, kbuf, vTbuf, attn, 0, 128, 128);
    attn_kernel<26><<<dim3(5, 768), 256, 0, stream>>>(qbuf, kbuf, vTbuf, attn, 128, 260, 388);

    // 4) proj GEMM: (24832x768) @ (768x768)^T + bias -> fp32 out
    gemm_bt<1><<<dim3(194, 6), 256, 0, stream>>>(attn, pwb, proj_b, nullptr, nullptr, nullptr, out);
}

// Round 2
// 411.923 us; speedup vs baseline: 1.2511x; 1.2511x over previous
//
#include <hip/hip_runtime.h>
#include <cstdint>
#include <cstddef>

typedef __attribute__((ext_vector_type(4))) float f32x4;
typedef __attribute__((ext_vector_type(8))) short bf16x8;

typedef const __attribute__((address_space(1))) void* gas_ptr;
typedef __attribute__((address_space(3))) void* las_ptr;

static __device__ __forceinline__ short f2bf(float f) {
    union { float f; uint32_t u; } v; v.f = f;
    uint32_t r = v.u + 0x7fffu + ((v.u >> 16) & 1u);
    return (short)(r >> 16);
}

// ---------------- fp32 -> bf16 conversion ----------------
__global__ void cvt_f32_bf16(const float* __restrict__ src, short* __restrict__ dst, int n4) {
    int i = blockIdx.x * blockDim.x + threadIdx.x;
    const int stride = gridDim.x * blockDim.x;
    for (; i < n4; i += stride) {
        const float4 v = reinterpret_cast<const float4*>(src)[i];
        short4 o;
        o.x = f2bf(v.x); o.y = f2bf(v.y); o.z = f2bf(v.z); o.w = f2bf(v.w);
        reinterpret_cast<short4*>(dst)[i] = o;
    }
}

// ---------------- bf16 GEMM  C = A (MxK) * B^T (NxK), K=768 ----------------
// (unchanged from round 1)
template<int MODE>
__global__ __launch_bounds__(256) void gemm_bt(
    const short* __restrict__ A, const short* __restrict__ Bw,
    const float* __restrict__ bias,
    short* __restrict__ qo, short* __restrict__ ko, short* __restrict__ vo,
    float* __restrict__ fo)
{
    constexpr int K = 768;
    constexpr int KT = K / 64;
    __shared__ __align__(16) short ldsA[128 * 64];
    __shared__ __align__(16) short ldsB[128 * 64];

    const int tid  = threadIdx.x;
    const int lane = tid & 63;
    const int wid  = tid >> 6;
    const int lrow = lane & 15;
    const int lgrp = lane >> 4;
    const int wr   = wid >> 1;
    const int wc   = wid & 1;
    const int m0   = blockIdx.x * 128;
    const int n0   = blockIdx.y * 128;

    f32x4 acc[4][4];
    #pragma unroll
    for (int i = 0; i < 4; ++i)
        #pragma unroll
        for (int j = 0; j < 4; ++j)
            acc[i][j] = f32x4{0.f, 0.f, 0.f, 0.f};

    for (int kt = 0; kt < KT; ++kt) {
        #pragma unroll
        for (int it = 0; it < 4; ++it) {
            const int c   = it * 256 + wid * 64 + lane;
            const int row = c >> 3;
            const int cb  = (c & 7) * 16;
            const int scb = cb ^ ((row & 7) << 4);
            const short* ga = A  + (size_t)(m0 + row) * K + kt * 64 + (scb >> 1);
            const short* gb = Bw + (size_t)(n0 + row) * K + kt * 64 + (scb >> 1);
            __builtin_amdgcn_global_load_lds((gas_ptr)ga, (las_ptr)((char*)ldsA + c * 16), 16, 0, 0);
            __builtin_amdgcn_global_load_lds((gas_ptr)gb, (las_ptr)((char*)ldsB + c * 16), 16, 0, 0);
        }
        __syncthreads();

        #pragma unroll
        for (int ks = 0; ks < 2; ++ks) {
            bf16x8 af[4], bfv[4];
            #pragma unroll
            for (int i = 0; i < 4; ++i) {
                const int r   = wr * 64 + i * 16 + lrow;
                const int byt = r * 128 + ((ks * 64 + lgrp * 16) ^ ((r & 7) << 4));
                af[i] = *reinterpret_cast<const bf16x8*>((const char*)ldsA + byt);
            }
            #pragma unroll
            for (int j = 0; j < 4; ++j) {
                const int r   = wc * 64 + j * 16 + lrow;
                const int byt = r * 128 + ((ks * 64 + lgrp * 16) ^ ((r & 7) << 4));
                bfv[j] = *reinterpret_cast<const bf16x8*>((const char*)ldsB + byt);
            }
            #pragma unroll
            for (int i = 0; i < 4; ++i)
                #pragma unroll
                for (int j = 0; j < 4; ++j)
                    acc[i][j] = __builtin_amdgcn_mfma_f32_16x16x32_bf16(af[i], bfv[j], acc[i][j], 0, 0, 0);
        }
        __syncthreads();
    }

    const int mb = m0 + wr * 64;
    const int nb = n0 + wc * 64;
    if constexpr (MODE == 0) {
        #pragma unroll
        for (int j = 0; j < 4; ++j) {
            const int c     = nb + j * 16 + lrow;
            const int which = c / 768;
            const int rem   = c - which * 768;
            const int hh    = rem >> 6;
            const int d     = rem & 63;
            const float sc  = (which == 0) ? 0.125f : 1.0f;
            const float bv  = bias[c];
            #pragma unroll
            for (int i = 0; i < 4; ++i) {
                #pragma unroll
                for (int r = 0; r < 4; ++r) {
                    const int m  = mb + i * 16 + lgrp * 4 + r;
                    const int bb = m / 388;
                    const int nn = m - bb * 388;
                    const short o = f2bf((acc[i][j][r] + bv) * sc);
                    const size_t bh = (size_t)bb * 12 + hh;
                    if (which == 0)      qo[(bh * 388 + nn) * 64 + d] = o;
                    else if (which == 1) ko[(bh * 388 + nn) * 64 + d] = o;
                    else                 vo[(bh * 64 + d) * 392 + nn] = o;
                }
            }
        }
    } else {
        #pragma unroll
        for (int i = 0; i < 4; ++i) {
            #pragma unroll
            for (int r = 0; r < 4; ++r) {
                const int m = mb + i * 16 + lgrp * 4 + r;
                #pragma unroll
                for (int j = 0; j < 4; ++j) {
                    const int c = nb + j * 16 + lrow;
                    fo[(size_t)m * 768 + c] = acc[i][j][r] + bias[c];
                }
            }
        }
    }
}

// ---------------- flash attention ----------------
constexpr int PSTR = 136;   // P row stride (bf16): 136 shorts = 68 dwords = 4 mod 32 banks

// Process one chunk of NT*16 keys starting at kbeg. Online softmax update.
template<int NT>
static __device__ __forceinline__ void attn_chunk(
    int kbeg, int k_len,
    const short* __restrict__ kbase, const short* __restrict__ vbase,
    const bf16x8 (&qf)[2], short* __restrict__ my,
    int lrow, int lgrp,
    float (&m)[4], float (&rs)[4], f32x4 (&oacc)[4])
{
    f32x4 sacc[NT];
    #pragma unroll
    for (int t = 0; t < NT; ++t) sacc[t] = f32x4{0.f, 0.f, 0.f, 0.f};

    #pragma unroll
    for (int t = 0; t < NT; ++t) {
        const int krow = kbeg + t * 16 + lrow;
        const int kc   = krow < k_len ? krow : k_len - 1;
        const short* kp = kbase + (size_t)kc * 64 + lgrp * 8;
        const bf16x8 k0 = *reinterpret_cast<const bf16x8*>(kp);
        const bf16x8 k1 = *reinterpret_cast<const bf16x8*>(kp + 32);
        sacc[t] = __builtin_amdgcn_mfma_f32_16x16x32_bf16(qf[0], k0, sacc[t], 0, 0, 0);
        sacc[t] = __builtin_amdgcn_mfma_f32_16x16x32_bf16(qf[1], k1, sacc[t], 0, 0, 0);
    }
    #pragma unroll
    for (int t = 0; t < NT; ++t) {
        if (kbeg + t * 16 + lrow >= k_len) {
            #pragma unroll
            for (int r = 0; r < 4; ++r) sacc[t][r] = -1e30f;
        }
    }
    // chunk row-max (over tiles in-lane, then over the 16 key lanes)
    float pmax[4] = {-1e30f, -1e30f, -1e30f, -1e30f};
    #pragma unroll
    for (int t = 0; t < NT; ++t)
        #pragma unroll
        for (int r = 0; r < 4; ++r) pmax[r] = fmaxf(pmax[r], sacc[t][r]);
    #pragma unroll
    for (int msk = 1; msk < 16; msk <<= 1)
        #pragma unroll
        for (int r = 0; r < 4; ++r) pmax[r] = fmaxf(pmax[r], __shfl_xor(pmax[r], msk, 64));

    float scale[4];
    #pragma unroll
    for (int r = 0; r < 4; ++r) {
        const float mn = fmaxf(m[r], pmax[r]);
        scale[r] = __expf(m[r] - mn);
        m[r] = mn;
    }
    // exp + partial sums, write P to per-wave LDS
    float ps[4] = {0.f, 0.f, 0.f, 0.f};
    #pragma unroll
    for (int t = 0; t < NT; ++t)
        #pragma unroll
        for (int r = 0; r < 4; ++r) {
            const float p = __expf(sacc[t][r] - m[r]);
            ps[r] += p;
            my[(lgrp * 4 + r) * PSTR + t * 16 + lrow] = f2bf(p);
        }
    #pragma unroll
    for (int msk = 1; msk < 16; msk <<= 1)
        #pragma unroll
        for (int r = 0; r < 4; ++r) ps[r] += __shfl_xor(ps[r], msk, 64);
    #pragma unroll
    for (int r = 0; r < 4; ++r) rs[r] = rs[r] * scale[r] + ps[r];
    #pragma unroll
    for (int dt = 0; dt < 4; ++dt)
        #pragma unroll
        for (int r = 0; r < 4; ++r) oacc[dt][r] *= scale[r];

    // O += P * V^T-chunk
    #pragma unroll
    for (int ks = 0; ks < NT / 2; ++ks) {
        const bf16x8 pf = *reinterpret_cast<const bf16x8*>(my + lrow * PSTR + ks * 32 + lgrp * 8);
        #pragma unroll
        for (int dt = 0; dt < 4; ++dt) {
            const bf16x8 vf = *reinterpret_cast<const bf16x8*>(
                vbase + (size_t)(dt * 16 + lrow) * 392 + kbeg + ks * 32 + lgrp * 8);
            oacc[dt] = __builtin_amdgcn_mfma_f32_16x16x32_bf16(pf, vf, oacc[dt], 0, 0, 0);
        }
    }
}

// grid (7, 768): bx 0..1 -> mt attn (q 0..127, k 0..127, 1 chunk)
//                bx 2..6 -> s  attn (q 128..387, k 0..387, 3 full chunks + 2-tile tail)
__global__ __launch_bounds__(256, 4) void attn_flash(
    const short* __restrict__ qb, const short* __restrict__ kb,
    const short* __restrict__ vT, short* __restrict__ ao)
{
    __shared__ __align__(16) short plds[4][16 * PSTR];

    const int tid  = threadIdx.x;
    const int lane = tid & 63;
    const int wid  = tid >> 6;
    const int lrow = lane & 15;
    const int lgrp = lane >> 4;
    const int bh   = blockIdx.y;
    const int bx   = blockIdx.x;

    int q_start, qend, k_len, nfull;
    bool tail;
    if (bx < 2) { q_start = bx * 64;             qend = 128; k_len = 128; nfull = 1; tail = false; }
    else        { q_start = 128 + (bx - 2) * 64; qend = 388; k_len = 388; nfull = 3; tail = true;  }

    const int q0 = q_start + wid * 16;
    if (q0 >= qend) return;   // no barriers in this kernel: safe

    const short* qbase = qb + (size_t)bh * 388 * 64;
    const short* kbase = kb + (size_t)bh * 388 * 64;
    const short* vbase = vT + (size_t)bh * 64 * 392;

    int qrow = q0 + lrow; if (qrow >= qend) qrow = qend - 1;
    bf16x8 qf[2];
    #pragma unroll
    for (int ks = 0; ks < 2; ++ks)
        qf[ks] = *reinterpret_cast<const bf16x8*>(qbase + (size_t)qrow * 64 + ks * 32 + lgrp * 8);

    float m[4]  = {-1e30f, -1e30f, -1e30f, -1e30f};
    float rs[4] = {0.f, 0.f, 0.f, 0.f};
    f32x4 oacc[4];
    #pragma unroll
    for (int dt = 0; dt < 4; ++dt) oacc[dt] = f32x4{0.f, 0.f, 0.f, 0.f};

    short* my = &plds[wid][0];
    for (int ch = 0; ch < nfull; ++ch)
        attn_chunk<8>(ch * 128, k_len, kbase, vbase, qf, my, lrow, lgrp, m, rs, oacc);
    if (tail)
        attn_chunk<2>(384, k_len, kbase, vbase, qf, my, lrow, lgrp, m, rs, oacc);

    const int b = bh / 12, h = bh - b * 12;
    float inv[4];
    #pragma unroll
    for (int r = 0; r < 4; ++r) inv[r] = 1.0f / rs[r];
    #pragma unroll
    for (int r = 0; r < 4; ++r) {
        const int qn = q0 + lgrp * 4 + r;
        if (qn < qend) {
            #pragma unroll
            for (int dt = 0; dt < 4; ++dt)
                ao[((size_t)b * 388 + qn) * 768 + h * 64 + dt * 16 + lrow] =
                    f2bf(oacc[dt][r] * inv[r]);
        }
    }
}

extern "C" void kernel_launch(void* const* d_in, const int* in_sizes, int n_in,
                              void* d_out, int out_size, void* d_ws, size_t ws_size,
                              hipStream_t stream) {
    (void)in_sizes; (void)n_in; (void)out_size; (void)ws_size;
    const float* x      = (const float*)d_in[0];
    const float* qkv_w  = (const float*)d_in[1];
    const float* qkv_b  = (const float*)d_in[2];
    const float* proj_w = (const float*)d_in[3];
    const float* proj_b = (const float*)d_in[4];
    float* out = (float*)d_out;

    const size_t SZ   = (size_t)24832 * 768;
    char* ws = (char*)d_ws;
    short* xb      = (short*)(ws);
    short* attn    = (short*)(ws);
    short* qbuf    = (short*)(ws + 2 * SZ);
    short* kbuf    = (short*)(ws + 4 * SZ);
    short* vTbuf   = (short*)(ws + 6 * SZ);
    const size_t VT_BYTES = (size_t)768 * 64 * 392 * 2 + 256;
    short* qwb     = (short*)(ws + 6 * SZ + VT_BYTES);
    short* pwb     = (short*)(ws + 6 * SZ + VT_BYTES + (size_t)2304 * 768 * 2);

    cvt_f32_bf16<<<2048, 256, 0, stream>>>(x,      xb,  (int)(SZ / 4));
    cvt_f32_bf16<<<512,  256, 0, stream>>>(qkv_w,  qwb, 2304 * 768 / 4);
    cvt_f32_bf16<<<256,  256, 0, stream>>>(proj_w, pwb, 768 * 768 / 4);

    gemm_bt<0><<<dim3(194, 18), 256, 0, stream>>>(xb, qwb, qkv_b, qbuf, kbuf, vTbuf, nullptr);

    attn_flash<<<dim3(7, 768), 256, 0, stream>>>(qbuf, kbuf, vTbuf, attn);

    gemm_bt<1><<<dim3(194, 6), 256, 0, stream>>>(attn, pwb, proj_b, nullptr, nullptr, nullptr, out);
}

// Round 3
// 380.682 us; speedup vs baseline: 1.3538x; 1.0821x over previous
//
#include <hip/hip_runtime.h>
#include <cstdint>
#include <cstddef>

typedef __attribute__((ext_vector_type(4))) float f32x4;
typedef __attribute__((ext_vector_type(8))) short bf16x8;

typedef const __attribute__((address_space(1))) void* gas_ptr;
typedef __attribute__((address_space(3))) void* las_ptr;

static __device__ __forceinline__ short f2bf(float f) {
    union { float f; uint32_t u; } v; v.f = f;
    uint32_t r = v.u + 0x7fffu + ((v.u >> 16) & 1u);
    return (short)(r >> 16);
}

// ---------------- fp32 -> bf16 conversion ----------------
__global__ void cvt_f32_bf16(const float* __restrict__ src, short* __restrict__ dst, int n4) {
    int i = blockIdx.x * blockDim.x + threadIdx.x;
    const int stride = gridDim.x * blockDim.x;
    for (; i < n4; i += stride) {
        const float4 v = reinterpret_cast<const float4*>(src)[i];
        short4 o;
        o.x = f2bf(v.x); o.y = f2bf(v.y); o.z = f2bf(v.z); o.w = f2bf(v.w);
        reinterpret_cast<short4*>(dst)[i] = o;
    }
}

// ---------------- bf16 GEMM  C = A (MxK) * B^T (NxK), K=768 ----------------
// 128x128 tile, BK=64, 4 waves (2x2).
// Round-3: T3-minimum pipelined double-buffer (stage next || compute cur,
// vmcnt(0)+s_barrier once per K-iter) + T1 XCD-bijective block swizzle
// (1D grid; consecutive wgid share the A panel -> by varies fastest).
// MODE 0: QKV epilogue -> scatter q(scaled)/k (B,H,388,64) and vT (B,H,64,392)
// MODE 1: proj epilogue -> fp32 out + bias
template<int MODE>
__global__ __launch_bounds__(256) void gemm_bt(
    const short* __restrict__ A, const short* __restrict__ Bw,
    const float* __restrict__ bias,
    short* __restrict__ qo, short* __restrict__ ko, short* __restrict__ vo,
    float* __restrict__ fo, int NB)
{
    constexpr int K = 768;
    constexpr int KT = 12;
    __shared__ __align__(16) short ldsA[2][128 * 64];
    __shared__ __align__(16) short ldsB[2][128 * 64];

    const int tid  = threadIdx.x;
    const int lane = tid & 63;
    const int wid  = tid >> 6;
    const int lrow = lane & 15;
    const int lgrp = lane >> 4;
    const int wr   = wid >> 1;
    const int wc   = wid & 1;

    // XCD-bijective remap (m204): blockIdx round-robins XCDs, so give each
    // XCD a contiguous wgid chunk. Within a chunk by varies fastest -> the
    // 128-row A panel is L2-resident across its 18 (or 6) column blocks.
    const int nwg = gridDim.x;
    const int q8  = nwg >> 3, r8 = nwg & 7;
    const int xcd = blockIdx.x & 7, bidx = blockIdx.x >> 3;
    const int wgid = (xcd < r8 ? xcd * (q8 + 1) : r8 * (q8 + 1) + (xcd - r8) * q8) + bidx;
    const int m0 = (wgid / NB) * 128;
    const int n0 = (wgid % NB) * 128;

    f32x4 acc[4][4];
    #pragma unroll
    for (int i = 0; i < 4; ++i)
        #pragma unroll
        for (int j = 0; j < 4; ++j)
            acc[i][j] = f32x4{0.f, 0.f, 0.f, 0.f};

    // stage one 128x64 A-tile + B-tile into buffer `buf` (8 DMA loads/thread)
    auto stage = [&](int kt, int buf) {
        #pragma unroll
        for (int it = 0; it < 4; ++it) {
            const int c   = it * 256 + wid * 64 + lane;
            const int row = c >> 3;
            const int scb = ((c & 7) * 16) ^ ((row & 7) << 4);   // inverse swizzle on SOURCE
            const short* ga = A  + (size_t)(m0 + row) * K + kt * 64 + (scb >> 1);
            const short* gb = Bw + (size_t)(n0 + row) * K + kt * 64 + (scb >> 1);
            __builtin_amdgcn_global_load_lds((gas_ptr)ga, (las_ptr)((char*)&ldsA[buf][0] + c * 16), 16, 0, 0);
            __builtin_amdgcn_global_load_lds((gas_ptr)gb, (las_ptr)((char*)&ldsB[buf][0] + c * 16), 16, 0, 0);
        }
    };

    // prologue: stage tile 0, wait, barrier
    stage(0, 0);
    asm volatile("s_waitcnt vmcnt(0)" ::: "memory");
    __builtin_amdgcn_s_barrier();

    for (int kt = 0; kt < KT; ++kt) {
        const int cur = kt & 1;
        if (kt + 1 < KT) stage(kt + 1, cur ^ 1);   // DMA flies under compute

        #pragma unroll
        for (int ks = 0; ks < 2; ++ks) {
            bf16x8 af[4], bfv[4];
            #pragma unroll
            for (int i = 0; i < 4; ++i) {
                const int r   = wr * 64 + i * 16 + lrow;
                const int byt = r * 128 + ((ks * 64 + lgrp * 16) ^ ((r & 7) << 4));
                af[i] = *reinterpret_cast<const bf16x8*>((const char*)&ldsA[cur][0] + byt);
            }
            #pragma unroll
            for (int j = 0; j < 4; ++j) {
                const int r   = wc * 64 + j * 16 + lrow;
                const int byt = r * 128 + ((ks * 64 + lgrp * 16) ^ ((r & 7) << 4));
                bfv[j] = *reinterpret_cast<const bf16x8*>((const char*)&ldsB[cur][0] + byt);
            }
            #pragma unroll
            for (int i = 0; i < 4; ++i)
                #pragma unroll
                for (int j = 0; j < 4; ++j)
                    acc[i][j] = __builtin_amdgcn_mfma_f32_16x16x32_bf16(af[i], bfv[j], acc[i][j], 0, 0, 0);
        }

        __builtin_amdgcn_sched_barrier(0);            // pin: nothing crosses into the drain
        asm volatile("s_waitcnt vmcnt(0)" ::: "memory");  // next tile landed (residual only)
        __builtin_amdgcn_s_barrier();                 // all waves: cur free to overwrite
    }

    const int mb = m0 + wr * 64;
    const int nb = n0 + wc * 64;
    if constexpr (MODE == 0) {
        #pragma unroll
        for (int j = 0; j < 4; ++j) {
            const int c     = nb + j * 16 + lrow;
            const int which = c / 768;
            const int rem   = c - which * 768;
            const int hh    = rem >> 6;
            const int d     = rem & 63;
            const float sc  = (which == 0) ? 0.125f : 1.0f;   // fold D^-0.5 into q
            const float bv  = bias[c];
            #pragma unroll
            for (int i = 0; i < 4; ++i) {
                #pragma unroll
                for (int r = 0; r < 4; ++r) {
                    const int m  = mb + i * 16 + lgrp * 4 + r;
                    const int bb = m / 388;
                    const int nn = m - bb * 388;
                    const short o = f2bf((acc[i][j][r] + bv) * sc);
                    const size_t bh = (size_t)bb * 12 + hh;
                    if (which == 0)      qo[(bh * 388 + nn) * 64 + d] = o;
                    else if (which == 1) ko[(bh * 388 + nn) * 64 + d] = o;
                    else                 vo[(bh * 64 + d) * 392 + nn] = o;  // transposed, padded
                }
            }
        }
    } else {
        #pragma unroll
        for (int i = 0; i < 4; ++i) {
            #pragma unroll
            for (int r = 0; r < 4; ++r) {
                const int m = mb + i * 16 + lgrp * 4 + r;
                #pragma unroll
                for (int j = 0; j < 4; ++j) {
                    const int c = nb + j * 16 + lrow;
                    fo[(size_t)m * 768 + c] = acc[i][j][r] + bias[c];
                }
            }
        }
    }
}

// ---------------- flash attention (unchanged from round 2) ----------------
constexpr int PSTR = 136;   // P row stride (bf16)

template<int NT>
static __device__ __forceinline__ void attn_chunk(
    int kbeg, int k_len,
    const short* __restrict__ kbase, const short* __restrict__ vbase,
    const bf16x8 (&qf)[2], short* __restrict__ my,
    int lrow, int lgrp,
    float (&m)[4], float (&rs)[4], f32x4 (&oacc)[4])
{
    f32x4 sacc[NT];
    #pragma unroll
    for (int t = 0; t < NT; ++t) sacc[t] = f32x4{0.f, 0.f, 0.f, 0.f};

    #pragma unroll
    for (int t = 0; t < NT; ++t) {
        const int krow = kbeg + t * 16 + lrow;
        const int kc   = krow < k_len ? krow : k_len - 1;
        const short* kp = kbase + (size_t)kc * 64 + lgrp * 8;
        const bf16x8 k0 = *reinterpret_cast<const bf16x8*>(kp);
        const bf16x8 k1 = *reinterpret_cast<const bf16x8*>(kp + 32);
        sacc[t] = __builtin_amdgcn_mfma_f32_16x16x32_bf16(qf[0], k0, sacc[t], 0, 0, 0);
        sacc[t] = __builtin_amdgcn_mfma_f32_16x16x32_bf16(qf[1], k1, sacc[t], 0, 0, 0);
    }
    #pragma unroll
    for (int t = 0; t < NT; ++t) {
        if (kbeg + t * 16 + lrow >= k_len) {
            #pragma unroll
            for (int r = 0; r < 4; ++r) sacc[t][r] = -1e30f;
        }
    }
    float pmax[4] = {-1e30f, -1e30f, -1e30f, -1e30f};
    #pragma unroll
    for (int t = 0; t < NT; ++t)
        #pragma unroll
        for (int r = 0; r < 4; ++r) pmax[r] = fmaxf(pmax[r], sacc[t][r]);
    #pragma unroll
    for (int msk = 1; msk < 16; msk <<= 1)
        #pragma unroll
        for (int r = 0; r < 4; ++r) pmax[r] = fmaxf(pmax[r], __shfl_xor(pmax[r], msk, 64));

    float scale[4];
    #pragma unroll
    for (int r = 0; r < 4; ++r) {
        const float mn = fmaxf(m[r], pmax[r]);
        scale[r] = __expf(m[r] - mn);
        m[r] = mn;
    }
    float ps[4] = {0.f, 0.f, 0.f, 0.f};
    #pragma unroll
    for (int t = 0; t < NT; ++t)
        #pragma unroll
        for (int r = 0; r < 4; ++r) {
            const float p = __expf(sacc[t][r] - m[r]);
            ps[r] += p;
            my[(lgrp * 4 + r) * PSTR + t * 16 + lrow] = f2bf(p);
        }
    #pragma unroll
    for (int msk = 1; msk < 16; msk <<= 1)
        #pragma unroll
        for (int r = 0; r < 4; ++r) ps[r] += __shfl_xor(ps[r], msk, 64);
    #pragma unroll
    for (int r = 0; r < 4; ++r) rs[r] = rs[r] * scale[r] + ps[r];
    #pragma unroll
    for (int dt = 0; dt < 4; ++dt)
        #pragma unroll
        for (int r = 0; r < 4; ++r) oacc[dt][r] *= scale[r];

    #pragma unroll
    for (int ks = 0; ks < NT / 2; ++ks) {
        const bf16x8 pf = *reinterpret_cast<const bf16x8*>(my + lrow * PSTR + ks * 32 + lgrp * 8);
        #pragma unroll
        for (int dt = 0; dt < 4; ++dt) {
            const bf16x8 vf = *reinterpret_cast<const bf16x8*>(
                vbase + (size_t)(dt * 16 + lrow) * 392 + kbeg + ks * 32 + lgrp * 8);
            oacc[dt] = __builtin_amdgcn_mfma_f32_16x16x32_bf16(pf, vf, oacc[dt], 0, 0, 0);
        }
    }
}

__global__ __launch_bounds__(256, 4) void attn_flash(
    const short* __restrict__ qb, const short* __restrict__ kb,
    const short* __restrict__ vT, short* __restrict__ ao)
{
    __shared__ __align__(16) short plds[4][16 * PSTR];

    const int tid  = threadIdx.x;
    const int lane = tid & 63;
    const int wid  = tid >> 6;
    const int lrow = lane & 15;
    const int lgrp = lane >> 4;
    const int bh   = blockIdx.y;
    const int bx   = blockIdx.x;

    int q_start, qend, k_len, nfull;
    bool tail;
    if (bx < 2) { q_start = bx * 64;             qend = 128; k_len = 128; nfull = 1; tail = false; }
    else        { q_start = 128 + (bx - 2) * 64; qend = 388; k_len = 388; nfull = 3; tail = true;  }

    const int q0 = q_start + wid * 16;
    if (q0 >= qend) return;   // no barriers in this kernel: safe

    const short* qbase = qb + (size_t)bh * 388 * 64;
    const short* kbase = kb + (size_t)bh * 388 * 64;
    const short* vbase = vT + (size_t)bh * 64 * 392;

    int qrow = q0 + lrow; if (qrow >= qend) qrow = qend - 1;
    bf16x8 qf[2];
    #pragma unroll
    for (int ks = 0; ks < 2; ++ks)
        qf[ks] = *reinterpret_cast<const bf16x8*>(qbase + (size_t)qrow * 64 + ks * 32 + lgrp * 8);

    float m[4]  = {-1e30f, -1e30f, -1e30f, -1e30f};
    float rs[4] = {0.f, 0.f, 0.f, 0.f};
    f32x4 oacc[4];
    #pragma unroll
    for (int dt = 0; dt < 4; ++dt) oacc[dt] = f32x4{0.f, 0.f, 0.f, 0.f};

    short* my = &plds[wid][0];
    for (int ch = 0; ch < nfull; ++ch)
        attn_chunk<8>(ch * 128, k_len, kbase, vbase, qf, my, lrow, lgrp, m, rs, oacc);
    if (tail)
        attn_chunk<2>(384, k_len, kbase, vbase, qf, my, lrow, lgrp, m, rs, oacc);

    const int b = bh / 12, h = bh - b * 12;
    float inv[4];
    #pragma unroll
    for (int r = 0; r < 4; ++r) inv[r] = 1.0f / rs[r];
    #pragma unroll
    for (int r = 0; r < 4; ++r) {
        const int qn = q0 + lgrp * 4 + r;
        if (qn < qend) {
            #pragma unroll
            for (int dt = 0; dt < 4; ++dt)
                ao[((size_t)b * 388 + qn) * 768 + h * 64 + dt * 16 + lrow] =
                    f2bf(oacc[dt][r] * inv[r]);
        }
    }
}

extern "C" void kernel_launch(void* const* d_in, const int* in_sizes, int n_in,
                              void* d_out, int out_size, void* d_ws, size_t ws_size,
                              hipStream_t stream) {
    (void)in_sizes; (void)n_in; (void)out_size; (void)ws_size;
    const float* x      = (const float*)d_in[0];
    const float* qkv_w  = (const float*)d_in[1];
    const float* qkv_b  = (const float*)d_in[2];
    const float* proj_w = (const float*)d_in[3];
    const float* proj_b = (const float*)d_in[4];
    float* out = (float*)d_out;

    const size_t SZ   = (size_t)24832 * 768;
    char* ws = (char*)d_ws;
    short* xb      = (short*)(ws);
    short* attn    = (short*)(ws);
    short* qbuf    = (short*)(ws + 2 * SZ);
    short* kbuf    = (short*)(ws + 4 * SZ);
    short* vTbuf   = (short*)(ws + 6 * SZ);
    const size_t VT_BYTES = (size_t)768 * 64 * 392 * 2 + 256;
    short* qwb     = (short*)(ws + 6 * SZ + VT_BYTES);
    short* pwb     = (short*)(ws + 6 * SZ + VT_BYTES + (size_t)2304 * 768 * 2);

    cvt_f32_bf16<<<2048, 256, 0, stream>>>(x,      xb,  (int)(SZ / 4));
    cvt_f32_bf16<<<512,  256, 0, stream>>>(qkv_w,  qwb, 2304 * 768 / 4);
    cvt_f32_bf16<<<256,  256, 0, stream>>>(proj_w, pwb, 768 * 768 / 4);

    gemm_bt<0><<<dim3(194 * 18), 256, 0, stream>>>(xb, qwb, qkv_b, qbuf, kbuf, vTbuf, nullptr, 18);

    attn_flash<<<dim3(7, 768), 256, 0, stream>>>(qbuf, kbuf, vTbuf, attn);

    gemm_bt<1><<<dim3(194 * 6), 256, 0, stream>>>(attn, pwb, proj_b, nullptr, nullptr, nullptr, out, 6);
}